// Round 2
// baseline (474.148 us; speedup 1.0000x reference)
//
#include <hip/hip_runtime.h>
#include <hip/hip_bf16.h>
#include <stdint.h>

#define S_LEN   4096
#define DIN     1280
#define DOUT    1280
#define N_LORA  4
#define R_LORA  16
#define M_TOT   32768               // B*S = 8*4096
#define KC      (DIN + N_LORA*R_LORA)   // 1344

typedef __attribute__((ext_vector_type(4))) float floatx4;
typedef __attribute__((ext_vector_type(8))) short shortx8;

typedef union { uint4 u; shortx8 s; } punx8;

static __device__ __forceinline__ unsigned short bf16_rne(float f) {
    union { float f; unsigned u; } v; v.f = f;
    unsigned u = v.u;
    u += 0x7fffu + ((u >> 16) & 1u);   // round-to-nearest-even
    return (unsigned short)(u >> 16);
}

static __device__ __forceinline__ void async16(const unsigned short* g, unsigned short* l) {
    __builtin_amdgcn_global_load_lds(
        (const __attribute__((address_space(1))) unsigned int*)g,
        (__attribute__((address_space(3))) unsigned int*)l, 16, 0, 0);
}

static __device__ __forceinline__ uint4 cvt8(const float* src) {
    const float4* p = (const float4*)src;
    float4 a = p[0], b = p[1];
    uint4 o;
    o.x = (unsigned)bf16_rne(a.x) | ((unsigned)bf16_rne(a.y) << 16);
    o.y = (unsigned)bf16_rne(a.z) | ((unsigned)bf16_rne(a.w) << 16);
    o.z = (unsigned)bf16_rne(b.x) | ((unsigned)bf16_rne(b.y) << 16);
    o.w = (unsigned)bf16_rne(b.z) | ((unsigned)bf16_rne(b.w) << 16);
    return o;
}

// ---- Kernel 1: Wcat[o, 0:1280] = W[o,:];  Wcat[o, 1280 + n*16 + r] = Bw[n,o,r]
__global__ __launch_bounds__(256) void k_build_wcat(const float* __restrict__ W,
                                                    const float* __restrict__ Bw,
                                                    unsigned short* __restrict__ Wcat) {
    int i = blockIdx.x * 256 + threadIdx.x;   // 215,040 threads
    int e = i * 8;                            // < 1280*1344
    int o = e / KC;
    int c = e - o * KC;                       // multiple of 8
    const float* src;
    if (c < DIN) {
        src = W + o * DIN + c;
    } else {
        int j = c - DIN;                      // 0..63, multiple of 8
        int n = j >> 4, r = j & 15;           // r in {0,8}; 8 floats contiguous in Bw
        src = Bw + (n * DOUT + o) * R_LORA + r;
    }
    *(uint4*)(Wcat + o * KC + c) = cvt8(src);
}

// ---- Kernel 2: A (N,R,DIN) fp32 -> Ab (64 x 1280) bf16 (flat contiguous)
__global__ __launch_bounds__(256) void k_convert_a(const float* __restrict__ A,
                                                   unsigned short* __restrict__ Ab) {
    int i = blockIdx.x * 256 + threadIdx.x;   // 10,240 threads
    int e = i * 8;                            // < 81,920
    *(uint4*)(Ab + e) = cvt8(A + e);
}

// ---- Kernel 3 (fused): convert x -> bf16 xg cols [0,1280), AND compute
// g = (scal*mask) * (x @ Ab^T) -> xg cols [1280,1344).  Barrier-free:
// each lane loads exactly its MFMA A-fragment (8 contiguous fp32) from x,
// converts in-register, stores bf16 to xg, feeds MFMA directly. Ab B-fragments
// are read per-lane from global (tiny, L1/L2-resident).
__global__ __launch_bounds__(256) void k_fused_x(const float* __restrict__ x,
                                                 const unsigned short* __restrict__ Ab,
                                                 const float* __restrict__ scalings,
                                                 const float* __restrict__ masks,
                                                 unsigned short* __restrict__ xg) {
    int tid = threadIdx.x;
    int wave = tid >> 6, lane = tid & 63;
    int mi = lane & 15, kq = lane >> 4;
    int m0 = blockIdx.x * 64;
    int m = m0 + wave * 16 + mi;              // this lane's A-fragment row

    const float* xrow = x + (size_t)m * DIN;
    unsigned short* xgrow = xg + (size_t)m * KC;

    floatx4 acc[4] = {};

    for (int k0 = 0; k0 < DIN; k0 += 32) {    // 40 steps, no barriers
        int k = k0 + kq * 8;
        punx8 xf; xf.u = cvt8(xrow + k);      // 8 fp32 -> 8 bf16
        *(uint4*)(xgrow + k) = xf.u;          // write-through to xg
#pragma unroll
        for (int ct = 0; ct < 4; ++ct) {
            shortx8 bf = *(const shortx8*)(Ab + (ct * 16 + mi) * DIN + k);
            acc[ct] = __builtin_amdgcn_mfma_f32_16x16x32_bf16(xf.s, bf, acc[ct], 0, 0, 0);
        }
    }

    // epilogue: D layout col(=rank idx)=mi, row(=m idx)=kq*4+reg  [R1-verified]
#pragma unroll
    for (int ct = 0; ct < 4; ++ct) {
        float sc = scalings[ct];
        int j = ct * 16 + mi;                 // rank index; adapter n == ct
#pragma unroll
        for (int reg = 0; reg < 4; ++reg) {
            int m2 = m0 + wave * 16 + kq * 4 + reg;
            int s = m2 & (S_LEN - 1);
            float wgt = sc * masks[ct * S_LEN + s];
            xg[(size_t)m2 * KC + DIN + j] = bf16_rne(acc[ct][reg] * wgt);
        }
    }
}

// ---- Kernel 4: out = xg @ Wcat^T + bias  (M=32768, N=1280, K=1344)
// m97 structure: BM=BN=128, BK=32, 256 threads (4 waves, 2x2), 16 MFMA/K-step.
// XCD swizzle: each XCD owns 32 row-blocks x 10 col-blocks so the A-tile and
// Wcat (3.7 MB combined) stay resident in that XCD's 4 MB L2.
__global__ __launch_bounds__(256) void k_main_gemm(const unsigned short* __restrict__ xg,
                                                   const unsigned short* __restrict__ Wcat,
                                                   const float* __restrict__ bias,
                                                   float* __restrict__ out) {
    __shared__ unsigned short As[128 * 32];
    __shared__ unsigned short Bs[128 * 32];
    int tid = threadIdx.x;
    int wave = tid >> 6, lane = tid & 63;

    // XCD-aware swizzle (dispatch round-robins consecutive bx across 8 XCDs)
    int bx = blockIdx.x;                  // 2560 blocks
    int xcd = bx & 7;
    int slot = bx >> 3;                   // 0..319
    int rb = xcd * 32 + slot / 10;        // 0..255
    int cb = slot % 10;                   // 0..9
    int m0 = rb * 128, n0 = cb * 128;

    int wr = wave >> 1, wc = wave & 1;
    int mi = lane & 15, kq = lane >> 4;

    // staging: 128x32 bf16 tile = 512 x 16B chunks; thread does chunks tid, tid+256
    int c0 = tid, c1 = tid + 256;
    int ar0 = c0 >> 2, ak0 = (c0 & 3) * 8;
    int ar1 = c1 >> 2, ak1 = (c1 & 3) * 8;

    floatx4 acc[4][4] = {};

    for (int k0 = 0; k0 < KC; k0 += 32) {   // 42 K-steps
        async16(xg   + (m0 + ar0) * KC + k0 + ak0, As + c0 * 8);
        async16(xg   + (m0 + ar1) * KC + k0 + ak1, As + c1 * 8);
        async16(Wcat + (n0 + ar0) * KC + k0 + ak0, Bs + c0 * 8);
        async16(Wcat + (n0 + ar1) * KC + k0 + ak1, Bs + c1 * 8);
        __syncthreads();
        shortx8 af[4], bf[4];
#pragma unroll
        for (int t = 0; t < 4; ++t) {
            af[t] = *(const shortx8*)(As + (wr * 64 + t * 16 + mi) * 32 + kq * 8);
            bf[t] = *(const shortx8*)(Bs + (wc * 64 + t * 16 + mi) * 32 + kq * 8);
        }
#pragma unroll
        for (int i = 0; i < 4; ++i)
#pragma unroll
            for (int j = 0; j < 4; ++j)
                acc[i][j] = __builtin_amdgcn_mfma_f32_16x16x32_bf16(af[i], bf[j], acc[i][j], 0, 0, 0);
        __syncthreads();
    }

    // epilogue: C/D layout col=lane&15, row=(lane>>4)*4+reg  [m89/m91-verified]
#pragma unroll
    for (int j = 0; j < 4; ++j) {
        int col = n0 + wc * 64 + j * 16 + mi;
        float bv = bias[col];
#pragma unroll
        for (int i = 0; i < 4; ++i) {
            int rbase = m0 + wr * 64 + i * 16 + kq * 4;
#pragma unroll
            for (int reg = 0; reg < 4; ++reg) {
                out[(size_t)(rbase + reg) * DOUT + col] = acc[i][j][reg] + bv;
            }
        }
    }
}

extern "C" void kernel_launch(void* const* d_in, const int* in_sizes, int n_in,
                              void* d_out, int out_size, void* d_ws, size_t ws_size,
                              hipStream_t stream) {
    const float* x     = (const float*)d_in[0];  // (8,4096,1280)
    const float* W     = (const float*)d_in[1];  // (1280,1280)
    const float* bias  = (const float*)d_in[2];  // (1280,)
    const float* A     = (const float*)d_in[3];  // (4,16,1280)
    const float* Bw    = (const float*)d_in[4];  // (4,1280,16)
    const float* scal  = (const float*)d_in[5];  // (4,)
    const float* masks = (const float*)d_in[6];  // (4,4096)
    float* out = (float*)d_out;

    unsigned short* xg   = (unsigned short*)d_ws;              // 32768 x 1344 bf16
    unsigned short* Wcat = xg + (size_t)M_TOT * KC;            // 1280 x 1344 bf16
    unsigned short* Ab   = Wcat + (size_t)DOUT * KC;           // 64 x 1280 bf16
    // total ws usage: 91,684,864 bytes

    k_convert_a<<<(N_LORA * R_LORA * DIN) / (8 * 256), 256, 0, stream>>>(A, Ab);
    k_build_wcat<<<(DOUT * KC) / (8 * 256), 256, 0, stream>>>(W, Bw, Wcat);
    k_fused_x<<<M_TOT / 64, 256, 0, stream>>>(x, Ab, scal, masks, xg);
    k_main_gemm<<<(M_TOT / 128) * (DOUT / 128), 256, 0, stream>>>(xg, Wcat, bias, out);
}

// Round 3
// 459.835 us; speedup vs baseline: 1.0311x; 1.0311x over previous
//
#include <hip/hip_runtime.h>
#include <hip/hip_bf16.h>
#include <stdint.h>

#define S_LEN   4096
#define DIN     1280
#define DOUT    1280
#define N_LORA  4
#define R_LORA  16
#define M_TOT   32768               // B*S = 8*4096
#define KC      (DIN + N_LORA*R_LORA)   // 1344
#define NR      64                  // N_LORA*R_LORA

typedef __attribute__((ext_vector_type(4))) float floatx4;
typedef __attribute__((ext_vector_type(8))) short shortx8;

typedef union { uint4 u; shortx8 s; } punx8;

static __device__ __forceinline__ unsigned short bf16_rne(float f) {
    union { float f; unsigned u; } v; v.f = f;
    unsigned u = v.u;
    u += 0x7fffu + ((u >> 16) & 1u);   // round-to-nearest-even
    return (unsigned short)(u >> 16);
}

static __device__ __forceinline__ void async16(const unsigned short* g, unsigned short* l) {
    __builtin_amdgcn_global_load_lds(
        (const __attribute__((address_space(1))) unsigned int*)g,
        (__attribute__((address_space(3))) unsigned int*)l, 16, 0, 0);
}

static __device__ __forceinline__ uint4 cvt8(const float* src) {
    const float4* p = (const float4*)src;
    float4 a = p[0], b = p[1];
    uint4 o;
    o.x = (unsigned)bf16_rne(a.x) | ((unsigned)bf16_rne(a.y) << 16);
    o.y = (unsigned)bf16_rne(a.z) | ((unsigned)bf16_rne(a.w) << 16);
    o.z = (unsigned)bf16_rne(b.x) | ((unsigned)bf16_rne(b.y) << 16);
    o.w = (unsigned)bf16_rne(b.z) | ((unsigned)bf16_rne(b.w) << 16);
    return o;
}

// ---- Kernel 1: x (fp32) -> xb (bf16, dense 32768 x 1280). Pure streaming.
__global__ __launch_bounds__(256) void k_convert_x(const float* __restrict__ x,
                                                   unsigned short* __restrict__ xb) {
    size_t e = ((size_t)blockIdx.x * 256 + threadIdx.x) * 8;
    *(uint4*)(xb + e) = cvt8(x + e);
}

// ---- Kernel 2: Wcat[o, 0:1280] = W[o,:];  Wcat[o, 1280 + n*16 + r] = Bw[n,o,r]
__global__ __launch_bounds__(256) void k_build_wcat(const float* __restrict__ W,
                                                    const float* __restrict__ Bw,
                                                    unsigned short* __restrict__ Wcat) {
    int i = blockIdx.x * 256 + threadIdx.x;   // 215,040 threads
    int e = i * 8;
    int o = e / KC;
    int c = e - o * KC;                       // multiple of 8
    const float* src;
    if (c < DIN) {
        src = W + o * DIN + c;
    } else {
        int j = c - DIN;                      // 0..63, multiple of 8
        int n = j >> 4, r = j & 15;           // r in {0,8}
        src = Bw + (n * DOUT + o) * R_LORA + r;
    }
    *(uint4*)(Wcat + o * KC + c) = cvt8(src);
}

// ---- Kernel 3: A (4,16,1280) fp32 -> Abp fragment-major bf16:
// Abp[((step*4 + ct)*64 + lane)*8 + jj] = A[ct*16 + (lane&15)][step*32 + (lane>>4)*8 + jj]
// so a wave's MFMA B-fragment load is ONE coalesced 1 KB read.
__global__ __launch_bounds__(256) void k_convert_abp(const float* __restrict__ A,
                                                     unsigned short* __restrict__ Abp) {
    int step = blockIdx.x;                    // 40 blocks
    int t = threadIdx.x;
    int ct = t >> 6, lane = t & 63;
    int mi = lane & 15, kq = lane >> 4;
    const float* src = A + (ct * 16 + mi) * DIN + step * 32 + kq * 8;
    *(uint4*)(Abp + ((size_t)(step * 4 + ct) * 64 + lane) * 8) = cvt8(src);
}

// ---- Kernel 4: g[m, n*16+r] = scal[n]*mask[n,s(m)] * (xb @ A^T)
// 1024 threads = 16 waves: wave = (kg, wv); kg = K-group (split-K x4, 320 K each),
// wv = row-group (16 rows each). Partials reduced via 64 KB LDS. 32 waves/CU.
__global__ __launch_bounds__(1024) void k_lora_g(const unsigned short* __restrict__ xb,
                                                 const unsigned short* __restrict__ Abp,
                                                 const float* __restrict__ scalings,
                                                 const float* __restrict__ masks,
                                                 unsigned short* __restrict__ g) {
    __shared__ float hs[4][64][64];           // [kg][row][rank] fp32 partials
    int tid = threadIdx.x;
    int wave = tid >> 6, lane = tid & 63;
    int kg = wave >> 2, wv = wave & 3;
    int mi = lane & 15, kq = lane >> 4;
    int m0 = blockIdx.x * 64;                 // 512 blocks

    const unsigned short* xrow = xb + (size_t)(m0 + wv * 16 + mi) * DIN;

    floatx4 acc[4] = {};
    for (int s = 0; s < 10; ++s) {
        int step = kg * 10 + s;               // global 32-wide k-step, 0..39
        int k = step * 32 + kq * 8;
        shortx8 xf = *(const shortx8*)(xrow + k);
#pragma unroll
        for (int ct = 0; ct < 4; ++ct) {
            shortx8 bfr = *(const shortx8*)(Abp + ((size_t)(step * 4 + ct) * 64 + lane) * 8);
            acc[ct] = __builtin_amdgcn_mfma_f32_16x16x32_bf16(xf, bfr, acc[ct], 0, 0, 0);
        }
    }
    // D layout: col(rank-local)=mi, row(m-local)=kq*4+reg
#pragma unroll
    for (int ct = 0; ct < 4; ++ct)
#pragma unroll
        for (int reg = 0; reg < 4; ++reg)
            hs[kg][wv * 16 + kq * 4 + reg][ct * 16 + mi] = acc[ct][reg];
    __syncthreads();

    // reduce 4 K-groups, scale, pack bf16, store. 1024 threads x 4 outputs.
    int r = tid >> 4;                         // 0..63 local row
    int c0 = (tid & 15) * 4;                  // 0..60 rank col (4-aligned)
    float4 s0 = *(const float4*)&hs[0][r][c0];
    float4 s1 = *(const float4*)&hs[1][r][c0];
    float4 s2 = *(const float4*)&hs[2][r][c0];
    float4 s3 = *(const float4*)&hs[3][r][c0];
    int n = c0 >> 4;                          // adapter (c0..c0+3 share it)
    int m = m0 + r;
    float wgt = scalings[n] * masks[n * S_LEN + (m & (S_LEN - 1))];
    float v0 = (s0.x + s1.x + s2.x + s3.x) * wgt;
    float v1 = (s0.y + s1.y + s2.y + s3.y) * wgt;
    float v2 = (s0.z + s1.z + s2.z + s3.z) * wgt;
    float v3 = (s0.w + s1.w + s2.w + s3.w) * wgt;
    uint2 packed;
    packed.x = (unsigned)bf16_rne(v0) | ((unsigned)bf16_rne(v1) << 16);
    packed.y = (unsigned)bf16_rne(v2) | ((unsigned)bf16_rne(v3) << 16);
    *(uint2*)(g + (size_t)m * NR + c0) = packed;
}

// ---- Kernel 5: out = [xb | g] @ Wcat^T + bias  (M=32768, N=1280, K=1344)
// m97 structure: BM=BN=128, BK=32, 256 threads (4 waves, 2x2), 16 MFMA/K-step.
// XCD swizzle: each XCD owns 32 row-blocks x 10 col-blocks (R2-verified: FETCH 373->101 MB).
__global__ __launch_bounds__(256) void k_main_gemm(const unsigned short* __restrict__ xb,
                                                   const unsigned short* __restrict__ g,
                                                   const unsigned short* __restrict__ Wcat,
                                                   const float* __restrict__ bias,
                                                   float* __restrict__ out) {
    __shared__ unsigned short As[128 * 32];
    __shared__ unsigned short Bs[128 * 32];
    int tid = threadIdx.x;
    int wave = tid >> 6, lane = tid & 63;

    int bx = blockIdx.x;                  // 2560 blocks
    int xcd = bx & 7;
    int slot = bx >> 3;                   // 0..319
    int rb = xcd * 32 + slot / 10;        // 0..255
    int cb = slot % 10;                   // 0..9
    int m0 = rb * 128, n0 = cb * 128;

    int wr = wave >> 1, wc = wave & 1;
    int mi = lane & 15, kq = lane >> 4;

    int c0 = tid, c1 = tid + 256;
    int ar0 = c0 >> 2, ak0 = (c0 & 3) * 8;
    int ar1 = c1 >> 2, ak1 = (c1 & 3) * 8;

    floatx4 acc[4][4] = {};

    for (int k0 = 0; k0 < KC; k0 += 32) {   // 42 K-steps: 40 from xb, 2 from g
        if (k0 < DIN) {
            async16(xb + (size_t)(m0 + ar0) * DIN + k0 + ak0, As + c0 * 8);
            async16(xb + (size_t)(m0 + ar1) * DIN + k0 + ak1, As + c1 * 8);
        } else {
            async16(g + (size_t)(m0 + ar0) * NR + (k0 - DIN) + ak0, As + c0 * 8);
            async16(g + (size_t)(m0 + ar1) * NR + (k0 - DIN) + ak1, As + c1 * 8);
        }
        async16(Wcat + (size_t)(n0 + ar0) * KC + k0 + ak0, Bs + c0 * 8);
        async16(Wcat + (size_t)(n0 + ar1) * KC + k0 + ak1, Bs + c1 * 8);
        __syncthreads();
        shortx8 af[4], bf[4];
#pragma unroll
        for (int t = 0; t < 4; ++t) {
            af[t] = *(const shortx8*)(As + (wr * 64 + t * 16 + mi) * 32 + kq * 8);
            bf[t] = *(const shortx8*)(Bs + (wc * 64 + t * 16 + mi) * 32 + kq * 8);
        }
#pragma unroll
        for (int i = 0; i < 4; ++i)
#pragma unroll
            for (int j = 0; j < 4; ++j)
                acc[i][j] = __builtin_amdgcn_mfma_f32_16x16x32_bf16(af[i], bf[j], acc[i][j], 0, 0, 0);
        __syncthreads();
    }

    // epilogue: C/D layout col=lane&15, row=(lane>>4)*4+reg
#pragma unroll
    for (int j = 0; j < 4; ++j) {
        int col = n0 + wc * 64 + j * 16 + mi;
        float bv = bias[col];
#pragma unroll
        for (int i = 0; i < 4; ++i) {
            int rbase = m0 + wr * 64 + i * 16 + kq * 4;
#pragma unroll
            for (int reg = 0; reg < 4; ++reg) {
                out[(size_t)(rbase + reg) * DOUT + col] = acc[i][j][reg] + bv;
            }
        }
    }
}

extern "C" void kernel_launch(void* const* d_in, const int* in_sizes, int n_in,
                              void* d_out, int out_size, void* d_ws, size_t ws_size,
                              hipStream_t stream) {
    const float* x     = (const float*)d_in[0];  // (8,4096,1280)
    const float* W     = (const float*)d_in[1];  // (1280,1280)
    const float* bias  = (const float*)d_in[2];  // (1280,)
    const float* A     = (const float*)d_in[3];  // (4,16,1280)
    const float* Bw    = (const float*)d_in[4];  // (4,1280,16)
    const float* scal  = (const float*)d_in[5];  // (4,)
    const float* masks = (const float*)d_in[6];  // (4,4096)
    float* out = (float*)d_out;

    unsigned short* xb   = (unsigned short*)d_ws;            // 32768 x 1280 bf16
    unsigned short* g    = xb + (size_t)M_TOT * DIN;         // 32768 x 64 bf16
    unsigned short* Wcat = g + (size_t)M_TOT * NR;           // 1280 x 1344 bf16
    unsigned short* Abp  = Wcat + (size_t)DOUT * KC;         // 40*4*64*8 bf16
    // total ws usage: 91,684,864 bytes (same as R2)

    k_convert_x<<<(M_TOT * DIN) / (8 * 256), 256, 0, stream>>>(x, xb);
    k_build_wcat<<<(DOUT * KC) / (8 * 256), 256, 0, stream>>>(W, Bw, Wcat);
    k_convert_abp<<<DIN / 32, 256, 0, stream>>>(A, Abp);
    k_lora_g<<<M_TOT / 64, 1024, 0, stream>>>(xb, Abp, scal, masks, g);
    k_main_gemm<<<(M_TOT / 128) * (DOUT / 128), 256, 0, stream>>>(xb, g, Wcat, bias, out);
}